// Round 4
// baseline (234.245 us; speedup 1.0000x reference)
//
#include <hip/hip_runtime.h>
#include <hip/hip_bf16.h>
#include <hip/hip_cooperative_groups.h>

namespace cg = cooperative_groups;

// B=64, S=2048, D=256, VOCAB=288. M=131072, T derived host-side.
//
// out[row] depends only on code = (day%7)*T + (tod%T) -> only 7*T=2016 distinct
// output rows:
//   prep_all : Htab[7T][256] bf16 = relu(W1[day]+W1[7+tod]+b1); W2S swizzle; TE probe
//   fused    : [cooperative] phase1 blocks 0..15 build Otab[2048][256] fp32 =
//              Htab @ W2 + b2 ; grid.sync ; phase2 all 512 blocks gather
//              out[row] = Otab[code(TE[row])], 256 rows/block contiguous.
// R4 purpose: single fused dispatch (~84us) exceeds the ~80us fill cutoff ->
// its rocprof counter row becomes visible (WRITE/FETCH/hbm_gbps) to arbitrate
// between "out-write wall" vs "misattributed poison fill" theories.
// Fallbacks: non-cooperative R2 path (otab+gather) and R0 temb_gemm.

typedef __bf16 bf16x4 __attribute__((ext_vector_type(4)));
typedef __bf16 bf16x8 __attribute__((ext_vector_type(8)));
typedef float  f32x4  __attribute__((ext_vector_type(4)));

#define M_TOTAL   131072
#define BM        128            // rows per block in GEMM kernels (4 waves x 32 rows)
#define FUSED_GRID 512           // 256 rows/block * 512 = 131072

// ws layout: [0,128K) W2S | [128K, +7T*512) Htab | flag | Otab

// ---- prep: Htab + W2S + TE dtype probe (verified R0/R2/R3) -----------------
__global__ __launch_bounds__(64) void prep_all(const float* __restrict__ W1,
                                               const float* __restrict__ b1,
                                               const float* __restrict__ W2,
                                               __bf16* __restrict__ W2S,
                                               __bf16* __restrict__ Htab,
                                               const int* __restrict__ TE32,
                                               int* __restrict__ flag, int T) {
    const int b = blockIdx.x, lane = threadIdx.x;
    const int nTab = 7 * T;
    if (b < nTab) {
        const float* __restrict__ wa = W1 + (b / T) * 256;
        const float* __restrict__ wb = W1 + (7 + b % T) * 256;
        f32x4 a = *(const f32x4*)(wa + lane * 4);
        f32x4 c = *(const f32x4*)(wb + lane * 4);
        f32x4 d = *(const f32x4*)(b1 + lane * 4);
        bf16x4 h;
#pragma unroll
        for (int j = 0; j < 4; ++j) h[j] = (__bf16)fmaxf(a[j] + c[j] + d[j], 0.0f);
        *(bf16x4*)(Htab + b * 256 + lane * 4) = h;
    } else {
        const int wb = b - nTab;               // 0..63
        // W2S chunk c = (nt*8+ks)*64+l ; elem j -> W2[ks*32+(l>>4)*8+j][nt*16+(l&15)]
#pragma unroll
        for (int q = 0; q < 2; ++q) {
            int c = (wb * 64 + lane) * 2 + q;  // 0..8191
            int l = c & 63, ksnt = c >> 6;
            int ks = ksnt & 7, nt = ksnt >> 3;
            int n  = nt * 16 + (l & 15);
            int k0 = ks * 32 + (l >> 4) * 8;
            bf16x8 w;
#pragma unroll
            for (int j = 0; j < 8; ++j) w[j] = (__bf16)W2[(k0 + j) * 256 + n];
            *(bf16x8*)(W2S + c * 8) = w;
        }
        if (wb == 0) {  // TE dtype probe: int64 => odd int32 words all zero
            int v = 0;
            for (int i = lane; i < 2048; i += 64) v |= TE32[2 * i + 1];
            unsigned long long nz = __ballot(v != 0);
            if (lane == 0) *flag = (nz == 0ull) ? 1 : 0;
        }
    }
}

// ---- device body: one otab block (rowBase window of 128 table rows) --------
__device__ __forceinline__ void otab_block_body(
        const __bf16* __restrict__ Htab, const __bf16* __restrict__ W2S,
        const float* __restrict__ b2, float* __restrict__ Otab, int T,
        __bf16* Bs, int blk)
{
    const int tid  = threadIdx.x;
    const int lane = tid & 63;
    const int wave = tid >> 6;
    const int m    = lane & 15;
    const int quad = lane >> 4;
    const int rowBase = blk * BM + wave * 32;
    const int nTab = 7 * T;

    int code[2];
#pragma unroll
    for (int t = 0; t < 2; ++t) {
        int row = rowBase + t * 16 + m;
        code[t] = row < nTab ? row : nTab - 1;   // clamp padded tail (never gathered)
    }
    bf16x8 hfrag[2][8];
#pragma unroll
    for (int t = 0; t < 2; ++t)
#pragma unroll
        for (int ks = 0; ks < 8; ++ks)
            hfrag[t][ks] = *(const bf16x8*)(Htab + code[t] * 256 + ks * 32 + quad * 8);

    const bf16x8* __restrict__ gsrc = (const bf16x8*)W2S + tid;
    bf16x8* __restrict__ ldst = (bf16x8*)Bs + tid;
    const bf16x8* __restrict__ lsrc = (const bf16x8*)Bs;

    bf16x8 stage[8];
#pragma unroll
    for (int q = 0; q < 8; ++q) stage[q] = gsrc[q * 256];        // group 0

    for (int g = 0; g < 4; ++g) {
#pragma unroll
        for (int q = 0; q < 8; ++q) ldst[q * 256] = stage[q];
        __syncthreads();
        if (g < 3) {
#pragma unroll
            for (int q = 0; q < 8; ++q) stage[q] = gsrc[(g + 1) * 2048 + q * 256];
        }
#pragma unroll
        for (int ntl = 0; ntl < 4; ++ntl) {
            const int nt = g * 4 + ntl;
            f32x4 acc0 = {0.f, 0.f, 0.f, 0.f};
            f32x4 acc1 = {0.f, 0.f, 0.f, 0.f};
#pragma unroll
            for (int ks = 0; ks < 8; ++ks) {
                bf16x8 wfrag = lsrc[(ntl * 8 + ks) * 64 + lane];   // A-operand (W2)
                acc0 = __builtin_amdgcn_mfma_f32_16x16x32_bf16(wfrag, hfrag[0][ks], acc0, 0, 0, 0);
                acc1 = __builtin_amdgcn_mfma_f32_16x16x32_bf16(wfrag, hfrag[1][ks], acc1, 0, 0, 0);
            }
            const f32x4 bias = *(const f32x4*)(b2 + nt * 16 + quad * 4);
            f32x4 v0, v1;
#pragma unroll
            for (int r = 0; r < 4; ++r) { v0[r] = acc0[r] + bias[r]; v1[r] = acc1[r] + bias[r]; }
            float* p0 = Otab + (rowBase + m) * 256 + nt * 16 + quad * 4;
            *(f32x4*)p0 = v0;
            *(f32x4*)(p0 + 16 * 256) = v1;
        }
        __syncthreads();
    }
}

// ---- fused cooperative kernel ----------------------------------------------
// 512 blocks x 256 thr. Phase 0: all blocks compute their 256 codes (TE loads
// overlap phase 1). Phase 1: blocks 0..otab_blocks-1 build Otab. grid.sync().
// Phase 2: block b copies rows [b*256, b*256+256): wave w owns 64 contiguous
// rows; per 16-row chunk, 16 loads then 16 stores (phase-separated).
__global__ __launch_bounds__(256, 2) void fused_otab_gather(
        const int*   __restrict__ TE32,
        const __bf16* __restrict__ Htab,
        const __bf16* __restrict__ W2S,
        const float* __restrict__ b2,
        const int*   __restrict__ flag,
        float* __restrict__ Otab,
        float* __restrict__ out, int T)
{
    __shared__ __bf16 Bs[4 * 8 * 512];   // 32 KB (phase 1 only)
    __shared__ int codes[256];           // 1 KB

    const int tid  = threadIdx.x;
    const int wave = tid >> 6;
    const int lane = tid & 63;

    // phase 0: codes for this block's 256 output rows
    {
        const int is64 = *flag;
        const int row = blockIdx.x * 256 + tid;
        int d32, t32;
        if (is64) { int4 te = *(const int4*)(TE32 + 4 * row); d32 = te.x; t32 = te.z; }
        else      { int2 te = *(const int2*)(TE32 + 2 * row); d32 = te.x; t32 = te.y; }
        int day = d32 % 7; if (day < 0) day += 7;
        int tod = t32 % T; if (tod < 0) tod += T;
        codes[tid] = day * T + tod;
    }

    // phase 1: Otab build on the first otab_blocks blocks
    const int otab_blocks = (7 * T + BM - 1) / BM;       // 16 for T=288
    if (blockIdx.x < otab_blocks)
        otab_block_body(Htab, W2S, b2, Otab, T, Bs, blockIdx.x);

    cg::this_grid().sync();

    // phase 2: gather/copy
    const float* srcB = Otab + lane * 4;
    float* dstW = out + ((size_t)blockIdx.x * 256 + wave * 64) * 256 + lane * 4;
#pragma unroll
    for (int chunk = 0; chunk < 4; ++chunk) {
        const int r0 = wave * 64 + chunk * 16;
        f32x4 v[16];
#pragma unroll
        for (int r = 0; r < 16; ++r)
            v[r] = *(const f32x4*)(srcB + (size_t)codes[r0 + r] * 256);
#pragma unroll
        for (int r = 0; r < 16; ++r)
            *(f32x4*)(dstW + (size_t)(chunk * 16 + r) * 256) = v[r];
    }
}

// ---- fallback: non-cooperative R2 path -------------------------------------
__global__ __launch_bounds__(256, 3) void otab_gemm(
        const __bf16* __restrict__ Htab, const __bf16* __restrict__ W2S,
        const float* __restrict__ b2, float* __restrict__ Otab, int T)
{
    __shared__ __bf16 Bs[4 * 8 * 512];
    otab_block_body(Htab, W2S, b2, Otab, T, Bs, blockIdx.x);
}

__global__ __launch_bounds__(256) void gather_out(
        const int*   __restrict__ TE32, const float* __restrict__ Otab,
        const int*   __restrict__ flag, float* __restrict__ out, int T)
{
    __shared__ int codes[64];
    const int tid  = threadIdx.x;
    const int wave = tid >> 6;
    const int lane = tid & 63;
    const int rowBase = blockIdx.x * 64;

    if (tid < 64) {
        const int is64 = *flag;
        const int row = rowBase + tid;
        int d32, t32;
        if (is64) { int4 te = *(const int4*)(TE32 + 4 * row); d32 = te.x; t32 = te.z; }
        else      { int2 te = *(const int2*)(TE32 + 2 * row); d32 = te.x; t32 = te.y; }
        int day = d32 % 7; if (day < 0) day += 7;
        int tod = t32 % T; if (tod < 0) tod += T;
        codes[tid] = day * T + tod;
    }
    __syncthreads();

    const float* src0 = Otab + lane * 4;
    float*       dst0 = out + (size_t)rowBase * 256 + (size_t)wave * 16 * 256 + lane * 4;
#pragma unroll
    for (int r = 0; r < 16; ++r) {
        const int c = codes[wave * 16 + r];
        f32x4 v = *(const f32x4*)(src0 + (size_t)c * 256);
        *(f32x4*)(dst0 + (size_t)r * 256) = v;
    }
}

// ---- fallback: verbatim proven R0 kernel -----------------------------------
__global__ __launch_bounds__(256, 3) void temb_gemm(
        const int*   __restrict__ TE32, const __bf16* __restrict__ Htab,
        const __bf16* __restrict__ W2S, const float* __restrict__ b2,
        const int*   __restrict__ flag, float* __restrict__ out, int T)
{
    __shared__ __bf16 Bs[4 * 8 * 512];

    const int is64 = *flag;
    const int tid  = threadIdx.x;
    const int wave = tid >> 6;
    const int lane = tid & 63;
    const int m    = lane & 15;
    const int quad = lane >> 4;
    const int rowBase = blockIdx.x * BM + wave * 32;

    int code[2];
#pragma unroll
    for (int t = 0; t < 2; ++t) {
        const int row = rowBase + t * 16 + m;
        int day, tod;
        if (is64) { int4 te = *(const int4*)(TE32 + 4 * row); day = te.x; tod = te.z; }
        else      { int2 te = *(const int2*)(TE32 + 2 * row); day = te.x; tod = te.y; }
        int dm = day % 7; if (dm < 0) dm += 7;
        int tm = tod % T; if (tm < 0) tm += T;
        code[t] = dm * T + tm;
    }
    bf16x8 hfrag[2][8];
#pragma unroll
    for (int t = 0; t < 2; ++t)
#pragma unroll
        for (int ks = 0; ks < 8; ++ks)
            hfrag[t][ks] = *(const bf16x8*)(Htab + code[t] * 256 + ks * 32 + quad * 8);

    const bf16x8* __restrict__ gsrc = (const bf16x8*)W2S + tid;
    bf16x8* __restrict__ ldst = (bf16x8*)Bs + tid;
    const bf16x8* __restrict__ lsrc = (const bf16x8*)Bs;

    bf16x8 stage[8];
#pragma unroll
    for (int q = 0; q < 8; ++q) stage[q] = gsrc[q * 256];

    for (int g = 0; g < 4; ++g) {
#pragma unroll
        for (int q = 0; q < 8; ++q) ldst[q * 256] = stage[q];
        __syncthreads();
        if (g < 3) {
#pragma unroll
            for (int q = 0; q < 8; ++q) stage[q] = gsrc[(g + 1) * 2048 + q * 256];
        }
#pragma unroll
        for (int ntl = 0; ntl < 4; ++ntl) {
            const int nt = g * 4 + ntl;
            f32x4 acc0 = {0.f, 0.f, 0.f, 0.f};
            f32x4 acc1 = {0.f, 0.f, 0.f, 0.f};
#pragma unroll
            for (int ks = 0; ks < 8; ++ks) {
                bf16x8 wfrag = lsrc[(ntl * 8 + ks) * 64 + lane];
                acc0 = __builtin_amdgcn_mfma_f32_16x16x32_bf16(wfrag, hfrag[0][ks], acc0, 0, 0, 0);
                acc1 = __builtin_amdgcn_mfma_f32_16x16x32_bf16(wfrag, hfrag[1][ks], acc1, 0, 0, 0);
            }
            const f32x4 bias = *(const f32x4*)(b2 + nt * 16 + quad * 4);
            f32x4 v0, v1;
#pragma unroll
            for (int r = 0; r < 4; ++r) { v0[r] = acc0[r] + bias[r]; v1[r] = acc1[r] + bias[r]; }
            float* p0 = out + (rowBase + m) * 256 + nt * 16 + quad * 4;
            *(f32x4*)p0 = v0;
            *(f32x4*)(p0 + 16 * 256) = v1;
        }
        __syncthreads();
    }
}

extern "C" void kernel_launch(void* const* d_in, const int* in_sizes, int n_in,
                              void* d_out, int out_size, void* d_ws, size_t ws_size,
                              hipStream_t stream) {
    const int*   TE = (const int*)  d_in[0];   // [B,S,2] integer words
    const float* W1 = (const float*)d_in[2];   // [7+T,256]
    const float* b1 = (const float*)d_in[3];   // [256]
    const float* W2 = (const float*)d_in[4];   // [256,256]
    const float* b2 = (const float*)d_in[5];   // [256]
    const int T = in_sizes[2] / 256 - 7;       // 288

    const int otab_blocks = (7 * T + BM - 1) / BM;        // 16 for T=288
    const int otab_rows   = otab_blocks * BM;             // 2048

    const size_t hoff = 131072;                           // Htab
    const size_t foff = hoff + (size_t)7 * T * 512;       // flag
    const size_t ooff = foff + 256;                       // Otab, 16B-aligned
    const size_t need = ooff + (size_t)otab_rows * 1024;

    __bf16* W2S  = (__bf16*)d_ws;
    __bf16* Htab = (__bf16*)((char*)d_ws + hoff);
    int*    flag = (int*)  ((char*)d_ws + foff);
    float*  Otab = (float*)((char*)d_ws + ooff);
    float*  out  = (float*)d_out;

    static int coop = -1;                     // host-side attr query, cached
    if (coop < 0) {
        int v = 0;
        hipDeviceGetAttribute(&v, hipDeviceAttributeCooperativeLaunch, 0);
        coop = v ? 1 : 0;
    }

    prep_all<<<7 * T + 64, 64, 0, stream>>>(W1, b1, W2, W2S, Htab, TE, flag, T);

    bool done = false;
    if (ws_size >= need) {
        if (coop) {
            const int* TEa = TE; const __bf16* Ha = Htab; const __bf16* Wa = W2S;
            const float* ba = b2; const int* fa = flag; float* Oa = Otab;
            float* oa = out; int Ta = T;
            void* args[] = {(void*)&TEa, (void*)&Ha, (void*)&Wa, (void*)&ba,
                            (void*)&fa, (void*)&Oa, (void*)&oa, (void*)&Ta};
            hipError_t e = hipLaunchCooperativeKernel((void*)fused_otab_gather,
                                                      dim3(FUSED_GRID), dim3(256),
                                                      args, 0, stream);
            done = (e == hipSuccess);
        }
        if (!done) {
            otab_gemm<<<otab_blocks, 256, 0, stream>>>(Htab, W2S, b2, Otab, T);
            gather_out<<<M_TOTAL / 64, 256, 0, stream>>>(TE, Otab, flag, out, T);
            done = true;
        }
    }
    if (!done)
        temb_gemm<<<M_TOTAL / BM, 256, 0, stream>>>(TE, Htab, W2S, b2, flag, out, T);
}

// Round 5
// 168.769 us; speedup vs baseline: 1.3880x; 1.3880x over previous
//
#include <hip/hip_runtime.h>
#include <hip/hip_bf16.h>

// B=64, S=2048, D=256, VOCAB=288. M=131072, T derived host-side.
//
// out[row] depends only on code = (day%7)*T + (tod%T) -> only 7*T=2016 distinct
// output rows:
//   prep_all  : Htab[7T][256] bf16 = relu(W1[day]+W1[7+tod]+b1); W2S swizzle; TE probe
//   otab_gemm : Otab[2048][256] fp32 = Htab @ W2 + b2   (16-block MFMA)
//   gather_out: out[row] = Otab[code(TE[row])]          (pure copy)
//
// R5: drop cooperative fusion (R4: -65us overhead, and 8 waves/CU starved the
// copy at 1.5 TB/s with NOTHING saturated -> latency-bound). Gather now runs
// R2's grid (2048 blocks = 32 waves/CU) with R4's batched inner (all 16 row
// loads in flight in v[16] before any store). Counters R4 proved: WRITE_SIZE
// exactly ideal, FETCH 25MB, zero conflicts -> only parallelism was missing.

typedef __bf16 bf16x4 __attribute__((ext_vector_type(4)));
typedef __bf16 bf16x8 __attribute__((ext_vector_type(8)));
typedef float  f32x4  __attribute__((ext_vector_type(4)));

#define M_TOTAL   131072
#define BM        128            // rows per block in GEMM kernels (4 waves x 32 rows)

// ws layout: [0,128K) W2S | [128K, +7T*512) Htab | flag | Otab

// ---- prep: Htab + W2S + TE dtype probe (verified R0/R2/R3/R4) --------------
__global__ __launch_bounds__(64) void prep_all(const float* __restrict__ W1,
                                               const float* __restrict__ b1,
                                               const float* __restrict__ W2,
                                               __bf16* __restrict__ W2S,
                                               __bf16* __restrict__ Htab,
                                               const int* __restrict__ TE32,
                                               int* __restrict__ flag, int T) {
    const int b = blockIdx.x, lane = threadIdx.x;
    const int nTab = 7 * T;
    if (b < nTab) {
        const float* __restrict__ wa = W1 + (b / T) * 256;
        const float* __restrict__ wb = W1 + (7 + b % T) * 256;
        f32x4 a = *(const f32x4*)(wa + lane * 4);
        f32x4 c = *(const f32x4*)(wb + lane * 4);
        f32x4 d = *(const f32x4*)(b1 + lane * 4);
        bf16x4 h;
#pragma unroll
        for (int j = 0; j < 4; ++j) h[j] = (__bf16)fmaxf(a[j] + c[j] + d[j], 0.0f);
        *(bf16x4*)(Htab + b * 256 + lane * 4) = h;
    } else {
        const int wb = b - nTab;               // 0..63
        // W2S chunk c = (nt*8+ks)*64+l ; elem j -> W2[ks*32+(l>>4)*8+j][nt*16+(l&15)]
#pragma unroll
        for (int q = 0; q < 2; ++q) {
            int c = (wb * 64 + lane) * 2 + q;  // 0..8191
            int l = c & 63, ksnt = c >> 6;
            int ks = ksnt & 7, nt = ksnt >> 3;
            int n  = nt * 16 + (l & 15);
            int k0 = ks * 32 + (l >> 4) * 8;
            bf16x8 w;
#pragma unroll
            for (int j = 0; j < 8; ++j) w[j] = (__bf16)W2[(k0 + j) * 256 + n];
            *(bf16x8*)(W2S + c * 8) = w;
        }
        if (wb == 0) {  // TE dtype probe: int64 => odd int32 words all zero
            int v = 0;
            for (int i = lane; i < 2048; i += 64) v |= TE32[2 * i + 1];
            unsigned long long nz = __ballot(v != 0);
            if (lane == 0) *flag = (nz == 0ull) ? 1 : 0;
        }
    }
}

// ---- device body: one otab block (rowBase window of 128 table rows) --------
__device__ __forceinline__ void otab_block_body(
        const __bf16* __restrict__ Htab, const __bf16* __restrict__ W2S,
        const float* __restrict__ b2, float* __restrict__ Otab, int T,
        __bf16* Bs, int blk)
{
    const int tid  = threadIdx.x;
    const int lane = tid & 63;
    const int wave = tid >> 6;
    const int m    = lane & 15;
    const int quad = lane >> 4;
    const int rowBase = blk * BM + wave * 32;
    const int nTab = 7 * T;

    int code[2];
#pragma unroll
    for (int t = 0; t < 2; ++t) {
        int row = rowBase + t * 16 + m;
        code[t] = row < nTab ? row : nTab - 1;   // clamp padded tail (never gathered)
    }
    bf16x8 hfrag[2][8];
#pragma unroll
    for (int t = 0; t < 2; ++t)
#pragma unroll
        for (int ks = 0; ks < 8; ++ks)
            hfrag[t][ks] = *(const bf16x8*)(Htab + code[t] * 256 + ks * 32 + quad * 8);

    const bf16x8* __restrict__ gsrc = (const bf16x8*)W2S + tid;
    bf16x8* __restrict__ ldst = (bf16x8*)Bs + tid;
    const bf16x8* __restrict__ lsrc = (const bf16x8*)Bs;

    bf16x8 stage[8];
#pragma unroll
    for (int q = 0; q < 8; ++q) stage[q] = gsrc[q * 256];        // group 0

    for (int g = 0; g < 4; ++g) {
#pragma unroll
        for (int q = 0; q < 8; ++q) ldst[q * 256] = stage[q];
        __syncthreads();
        if (g < 3) {
#pragma unroll
            for (int q = 0; q < 8; ++q) stage[q] = gsrc[(g + 1) * 2048 + q * 256];
        }
#pragma unroll
        for (int ntl = 0; ntl < 4; ++ntl) {
            const int nt = g * 4 + ntl;
            f32x4 acc0 = {0.f, 0.f, 0.f, 0.f};
            f32x4 acc1 = {0.f, 0.f, 0.f, 0.f};
#pragma unroll
            for (int ks = 0; ks < 8; ++ks) {
                bf16x8 wfrag = lsrc[(ntl * 8 + ks) * 64 + lane];   // A-operand (W2)
                acc0 = __builtin_amdgcn_mfma_f32_16x16x32_bf16(wfrag, hfrag[0][ks], acc0, 0, 0, 0);
                acc1 = __builtin_amdgcn_mfma_f32_16x16x32_bf16(wfrag, hfrag[1][ks], acc1, 0, 0, 0);
            }
            const f32x4 bias = *(const f32x4*)(b2 + nt * 16 + quad * 4);
            f32x4 v0, v1;
#pragma unroll
            for (int r = 0; r < 4; ++r) { v0[r] = acc0[r] + bias[r]; v1[r] = acc1[r] + bias[r]; }
            float* p0 = Otab + (rowBase + m) * 256 + nt * 16 + quad * 4;
            *(f32x4*)p0 = v0;
            *(f32x4*)(p0 + 16 * 256) = v1;
        }
        __syncthreads();
    }
}

__global__ __launch_bounds__(256, 3) void otab_gemm(
        const __bf16* __restrict__ Htab, const __bf16* __restrict__ W2S,
        const float* __restrict__ b2, float* __restrict__ Otab, int T)
{
    __shared__ __bf16 Bs[4 * 8 * 512];
    otab_block_body(Htab, W2S, b2, Otab, T, Bs, blockIdx.x);
}

// ---- gather: out[row] = Otab[code(TE[row])] --------------------------------
// 2048 blocks x 256 thr = 32 waves/CU. Each wave: 16 rows; all 16 indexed
// 1KB loads issued into v[16] (256 cache lines in flight) before 16 stores.
__global__ __launch_bounds__(256) void gather_out(
        const int*   __restrict__ TE32,  // [M,2] int32 or int64 word view
        const float* __restrict__ Otab,  // [otab_rows,256] fp32
        const int*   __restrict__ flag,  // 1 if TE is int64
        float* __restrict__ out, int T)  // [M,256] fp32
{
    __shared__ int codes[64];
    const int tid  = threadIdx.x;
    const int wave = tid >> 6;
    const int lane = tid & 63;
    const int rowBase = blockIdx.x * 64;

    if (tid < 64) {
        const int is64 = *flag;
        const int row = rowBase + tid;
        int d32, t32;
        if (is64) { int4 te = *(const int4*)(TE32 + 4 * row); d32 = te.x; t32 = te.z; }
        else      { int2 te = *(const int2*)(TE32 + 2 * row); d32 = te.x; t32 = te.y; }
        // reference-exact: int32 cast then Python-style mod (non-negative)
        int day = d32 % 7; if (day < 0) day += 7;
        int tod = t32 % T; if (tod < 0) tod += T;
        codes[tid] = day * T + tod;
    }
    __syncthreads();

    const float* src0 = Otab + lane * 4;
    float*       dst0 = out + ((size_t)rowBase + wave * 16) * 256 + lane * 4;
    f32x4 v[16];
#pragma unroll
    for (int r = 0; r < 16; ++r)
        v[r] = *(const f32x4*)(src0 + (size_t)codes[wave * 16 + r] * 256);
#pragma unroll
    for (int r = 0; r < 16; ++r)
        *(f32x4*)(dst0 + (size_t)r * 256) = v[r];
}

// ---- fallback: verbatim proven R0 kernel -----------------------------------
__global__ __launch_bounds__(256, 3) void temb_gemm(
        const int*   __restrict__ TE32, const __bf16* __restrict__ Htab,
        const __bf16* __restrict__ W2S, const float* __restrict__ b2,
        const int*   __restrict__ flag, float* __restrict__ out, int T)
{
    __shared__ __bf16 Bs[4 * 8 * 512];

    const int is64 = *flag;
    const int tid  = threadIdx.x;
    const int wave = tid >> 6;
    const int lane = tid & 63;
    const int m    = lane & 15;
    const int quad = lane >> 4;
    const int rowBase = blockIdx.x * BM + wave * 32;

    int code[2];
#pragma unroll
    for (int t = 0; t < 2; ++t) {
        const int row = rowBase + t * 16 + m;
        int day, tod;
        if (is64) { int4 te = *(const int4*)(TE32 + 4 * row); day = te.x; tod = te.z; }
        else      { int2 te = *(const int2*)(TE32 + 2 * row); day = te.x; tod = te.y; }
        int dm = day % 7; if (dm < 0) dm += 7;
        int tm = tod % T; if (tm < 0) tm += T;
        code[t] = dm * T + tm;
    }
    bf16x8 hfrag[2][8];
#pragma unroll
    for (int t = 0; t < 2; ++t)
#pragma unroll
        for (int ks = 0; ks < 8; ++ks)
            hfrag[t][ks] = *(const bf16x8*)(Htab + code[t] * 256 + ks * 32 + quad * 8);

    const bf16x8* __restrict__ gsrc = (const bf16x8*)W2S + tid;
    bf16x8* __restrict__ ldst = (bf16x8*)Bs + tid;
    const bf16x8* __restrict__ lsrc = (const bf16x8*)Bs;

    bf16x8 stage[8];
#pragma unroll
    for (int q = 0; q < 8; ++q) stage[q] = gsrc[q * 256];

    for (int g = 0; g < 4; ++g) {
#pragma unroll
        for (int q = 0; q < 8; ++q) ldst[q * 256] = stage[q];
        __syncthreads();
        if (g < 3) {
#pragma unroll
            for (int q = 0; q < 8; ++q) stage[q] = gsrc[(g + 1) * 2048 + q * 256];
        }
#pragma unroll
        for (int ntl = 0; ntl < 4; ++ntl) {
            const int nt = g * 4 + ntl;
            f32x4 acc0 = {0.f, 0.f, 0.f, 0.f};
            f32x4 acc1 = {0.f, 0.f, 0.f, 0.f};
#pragma unroll
            for (int ks = 0; ks < 8; ++ks) {
                bf16x8 wfrag = lsrc[(ntl * 8 + ks) * 64 + lane];
                acc0 = __builtin_amdgcn_mfma_f32_16x16x32_bf16(wfrag, hfrag[0][ks], acc0, 0, 0, 0);
                acc1 = __builtin_amdgcn_mfma_f32_16x16x32_bf16(wfrag, hfrag[1][ks], acc1, 0, 0, 0);
            }
            const f32x4 bias = *(const f32x4*)(b2 + nt * 16 + quad * 4);
            f32x4 v0, v1;
#pragma unroll
            for (int r = 0; r < 4; ++r) { v0[r] = acc0[r] + bias[r]; v1[r] = acc1[r] + bias[r]; }
            float* p0 = out + (rowBase + m) * 256 + nt * 16 + quad * 4;
            *(f32x4*)p0 = v0;
            *(f32x4*)(p0 + 16 * 256) = v1;
        }
        __syncthreads();
    }
}

extern "C" void kernel_launch(void* const* d_in, const int* in_sizes, int n_in,
                              void* d_out, int out_size, void* d_ws, size_t ws_size,
                              hipStream_t stream) {
    const int*   TE = (const int*)  d_in[0];   // [B,S,2] integer words
    const float* W1 = (const float*)d_in[2];   // [7+T,256]
    const float* b1 = (const float*)d_in[3];   // [256]
    const float* W2 = (const float*)d_in[4];   // [256,256]
    const float* b2 = (const float*)d_in[5];   // [256]
    const int T = in_sizes[2] / 256 - 7;       // 288

    const int otab_blocks = (7 * T + BM - 1) / BM;        // 16 for T=288
    const int otab_rows   = otab_blocks * BM;             // 2048

    const size_t hoff = 131072;                           // Htab
    const size_t foff = hoff + (size_t)7 * T * 512;       // flag
    const size_t ooff = foff + 256;                       // Otab, 16B-aligned
    const size_t need = ooff + (size_t)otab_rows * 1024;

    __bf16* W2S  = (__bf16*)d_ws;
    __bf16* Htab = (__bf16*)((char*)d_ws + hoff);
    int*    flag = (int*)  ((char*)d_ws + foff);
    float*  Otab = (float*)((char*)d_ws + ooff);
    float*  out  = (float*)d_out;

    prep_all<<<7 * T + 64, 64, 0, stream>>>(W1, b1, W2, W2S, Htab, TE, flag, T);
    if (ws_size >= need) {
        otab_gemm<<<otab_blocks, 256, 0, stream>>>(Htab, W2S, b2, Otab, T);
        gather_out<<<M_TOTAL / 64, 256, 0, stream>>>(TE, Otab, flag, out, T);
    } else {
        temb_gemm<<<M_TOTAL / BM, 256, 0, stream>>>(TE, Htab, W2S, b2, flag, out, T);
    }
}

// Round 6
// 165.808 us; speedup vs baseline: 1.4128x; 1.0179x over previous
//
#include <hip/hip_runtime.h>
#include <hip/hip_bf16.h>

// B=64, S=2048, D=256, VOCAB=288. M=131072, T derived host-side.
// Htab[day*T+tod] = relu(W1[day]+W1[7+tod]+b1) bf16 [7T][256]  (2016 rows)
// W2S = W2 swizzled to MFMA fragment-linear bf16.
// Main: OPERAND-SWAPPED mfma: A-op = W2 frag (LDS, block-shared),
//       B-op = h frag (direct from Htab); contiguous dwordx4 stores.
//
// R6 (final): revert to the 2-dispatch R0 structure. Session decomposition
// (anchored by R4's directly-measured 89.2us fused kernel) shows fixed harness
// overhead F ~= 142us (512MiB ws poison @82us + out poison + gaps) and
// temb_gemm ~= 21.4us == the output-write roofline (134.2MB / 6.3TB/s achievable
// = 21.3us). Otab/gather variants (R2/R3/R5) all pay +2-8us for the extra
// dispatch + table round-trip. This IS the floor for the controllable part.

typedef __bf16 bf16x4 __attribute__((ext_vector_type(4)));
typedef __bf16 bf16x8 __attribute__((ext_vector_type(8)));
typedef float  f32x4  __attribute__((ext_vector_type(4)));

#define M_TOTAL   131072
#define BM        128            // rows per block (4 waves x 32 rows)

// ws: [0,131072) W2S ; [131072, +7T*512) Htab ; then flag

// ---- prep: Htab + W2S + TE dtype probe (verified R0..R5) -------------------
__global__ __launch_bounds__(64) void prep_all(const float* __restrict__ W1,
                                               const float* __restrict__ b1,
                                               const float* __restrict__ W2,
                                               __bf16* __restrict__ W2S,
                                               __bf16* __restrict__ Htab,
                                               const int* __restrict__ TE32,
                                               int* __restrict__ flag, int T) {
    const int b = blockIdx.x, lane = threadIdx.x;
    const int nTab = 7 * T;
    if (b < nTab) {
        const float* __restrict__ wa = W1 + (b / T) * 256;
        const float* __restrict__ wb = W1 + (7 + b % T) * 256;
        f32x4 a = *(const f32x4*)(wa + lane * 4);
        f32x4 c = *(const f32x4*)(wb + lane * 4);
        f32x4 d = *(const f32x4*)(b1 + lane * 4);
        bf16x4 h;
#pragma unroll
        for (int j = 0; j < 4; ++j) h[j] = (__bf16)fmaxf(a[j] + c[j] + d[j], 0.0f);
        *(bf16x4*)(Htab + b * 256 + lane * 4) = h;
    } else {
        const int wb = b - nTab;               // 0..63
        // W2S chunk c = (nt*8+ks)*64+l ; elem j -> W2[ks*32+(l>>4)*8+j][nt*16+(l&15)]
#pragma unroll
        for (int q = 0; q < 2; ++q) {
            int c = (wb * 64 + lane) * 2 + q;  // 0..8191
            int l = c & 63, ksnt = c >> 6;
            int ks = ksnt & 7, nt = ksnt >> 3;
            int n  = nt * 16 + (l & 15);
            int k0 = ks * 32 + (l >> 4) * 8;
            bf16x8 w;
#pragma unroll
            for (int j = 0; j < 8; ++j) w[j] = (__bf16)W2[(k0 + j) * 256 + n];
            *(bf16x8*)(W2S + c * 8) = w;
        }
        if (wb == 0) {  // TE dtype probe: int64 => odd int32 words all zero
            int v = 0;
            for (int i = lane; i < 2048; i += 64) v |= TE32[2 * i + 1];
            unsigned long long nz = __ballot(v != 0);
            if (lane == 0) *flag = (nz == 0ull) ? 1 : 0;
        }
    }
}

// ---- main: write-roofline-bound fused gather+GEMM (measured ~21.4us) -------
__global__ __launch_bounds__(256, 3) void temb_gemm(
        const int*   __restrict__ TE32,  // [M,2] int32 or int64 word view
        const __bf16* __restrict__ Htab, // [7T][256] bf16
        const __bf16* __restrict__ W2S,  // fragment-linear bf16 (128 KB)
        const float* __restrict__ b2,    // [256]
        const int*   __restrict__ flag,  // 1 if TE is int64
        float* __restrict__ out, int T)  // [M,256] fp32
{
    __shared__ __bf16 Bs[4 * 8 * 512];   // 32 KB: one group = 4 n-tiles of W2 frags

    const int is64 = *flag;              // wave-uniform
    const int tid  = threadIdx.x;
    const int wave = tid >> 6;
    const int lane = tid & 63;
    const int m    = lane & 15;
    const int quad = lane >> 4;
    const int rowBase = blockIdx.x * BM + wave * 32;

    // ---- h fragments as MFMA B-operand: lane holds h[row=rowBase+t*16+m][k]
    int code[2];
#pragma unroll
    for (int t = 0; t < 2; ++t) {
        const int row = rowBase + t * 16 + m;
        int day, tod;
        if (is64) { int4 te = *(const int4*)(TE32 + 4 * row); day = te.x; tod = te.z; }
        else      { int2 te = *(const int2*)(TE32 + 2 * row); day = te.x; tod = te.y; }
        int dm = day % 7; if (dm < 0) dm += 7;    // Python-style mod (safety)
        int tm = tod % T; if (tm < 0) tm += T;
        code[t] = dm * T + tm;
    }
    bf16x8 hfrag[2][8];
#pragma unroll
    for (int t = 0; t < 2; ++t)
#pragma unroll
        for (int ks = 0; ks < 8; ++ks)
            hfrag[t][ks] = *(const bf16x8*)(Htab + code[t] * 256 + ks * 32 + quad * 8);

    // ---- staging pipeline: group g = n-tiles 4g..4g+3 (32 KB of W2S) -------
    const bf16x8* __restrict__ gsrc = (const bf16x8*)W2S + tid;  // + q*256 + g*2048
    bf16x8* __restrict__ ldst = (bf16x8*)Bs + tid;               // + q*256
    const bf16x8* __restrict__ lsrc = (const bf16x8*)Bs;

    bf16x8 stage[8];
#pragma unroll
    for (int q = 0; q < 8; ++q) stage[q] = gsrc[q * 256];        // group 0

    for (int g = 0; g < 4; ++g) {
#pragma unroll
        for (int q = 0; q < 8; ++q) ldst[q * 256] = stage[q];
        __syncthreads();                       // Bs[g] visible to all waves
        if (g < 3) {                           // prefetch next group into regs
#pragma unroll
            for (int q = 0; q < 8; ++q) stage[q] = gsrc[(g + 1) * 2048 + q * 256];
        }
#pragma unroll
        for (int ntl = 0; ntl < 4; ++ntl) {
            const int nt = g * 4 + ntl;
            f32x4 acc0 = {0.f, 0.f, 0.f, 0.f};
            f32x4 acc1 = {0.f, 0.f, 0.f, 0.f};
#pragma unroll
            for (int ks = 0; ks < 8; ++ks) {
                bf16x8 wfrag = lsrc[(ntl * 8 + ks) * 64 + lane];   // A-operand (W2)
                acc0 = __builtin_amdgcn_mfma_f32_16x16x32_bf16(wfrag, hfrag[0][ks], acc0, 0, 0, 0);
                acc1 = __builtin_amdgcn_mfma_f32_16x16x32_bf16(wfrag, hfrag[1][ks], acc1, 0, 0, 0);
            }
            // D[m=quad*4+r][n=lane&15] = out[rowBase+t*16+(lane&15)][nt*16+quad*4+r]
            const f32x4 bias = *(const f32x4*)(b2 + nt * 16 + quad * 4);
            f32x4 v0, v1;
#pragma unroll
            for (int r = 0; r < 4; ++r) { v0[r] = acc0[r] + bias[r]; v1[r] = acc1[r] + bias[r]; }
            float* p0 = out + (rowBase + m) * 256 + nt * 16 + quad * 4;
            *(f32x4*)p0 = v0;
            *(f32x4*)(p0 + 16 * 256) = v1;
        }
        __syncthreads();                       // all waves done reading Bs[g]
    }
}

extern "C" void kernel_launch(void* const* d_in, const int* in_sizes, int n_in,
                              void* d_out, int out_size, void* d_ws, size_t ws_size,
                              hipStream_t stream) {
    const int*   TE = (const int*)  d_in[0];   // [B,S,2] integer words
    const float* W1 = (const float*)d_in[2];   // [7+T,256]
    const float* b1 = (const float*)d_in[3];   // [256]
    const float* W2 = (const float*)d_in[4];   // [256,256]
    const float* b2 = (const float*)d_in[5];   // [256]
    const int T = in_sizes[2] / 256 - 7;       // 288

    __bf16* W2S  = (__bf16*)d_ws;                         // 128 KB
    __bf16* Htab = (__bf16*)((char*)d_ws + 131072);       // 7*T*512 bytes
    int*    flag = (int*)((char*)d_ws + 131072 + (size_t)7 * T * 512);
    float*  out  = (float*)d_out;

    prep_all<<<7 * T + 64, 64, 0, stream>>>(W1, b1, W2, W2S, Htab, TE, flag, T);
    temb_gemm<<<M_TOTAL / BM, 256, 0, stream>>>(TE, Htab, W2S, b2, flag, out, T);
}